// Round 4
// baseline (134.105 us; speedup 1.0000x reference)
//
#include <hip/hip_runtime.h>
#include <cstdint>

#define B_    2048
#define T_    2048
#define TD    7            // transform leading dim (C+2)
#define NCH   64           // chunks over T
#define L_    32           // chunk length (NCH*L_ == T_)
#define NB    4            // 8-step sub-blocks per chunk
#define IDENT 0x4688u      // 0|1<<3|2<<6|3<<9|4<<12

// ---- 8-step vector loader (x: 10x float4, mask: 2x int4) ----
__device__ __forceinline__ void loadx(const float* __restrict__ xb,
                                      const int* __restrict__ mb, int kk,
                                      float4 (&X)[10], int4 (&M)[2]) {
    const float4* px = (const float4*)(xb + (size_t)kk * 40);
#pragma unroll
    for (int q = 0; q < 10; ++q) X[q] = px[q];
    const int4* pm = (const int4*)(mb + kk * 8);
#pragma unroll
    for (int q = 0; q < 2; ++q) M[q] = pm[q];
}

// ---- max-plus operator composition over 8 steps ----
template<int LSTART>
__device__ __forceinline__ void compose_block(
    const float4 (&X)[10], const int4 (&M)[2],
    float (&A)[5][5], const float (&tr)[5][5])
{
    float xf[40];
#pragma unroll
    for (int q = 0; q < 10; ++q) {
        xf[4*q] = X[q].x; xf[4*q+1] = X[q].y; xf[4*q+2] = X[q].z; xf[4*q+3] = X[q].w;
    }
    int ml[8];
#pragma unroll
    for (int q = 0; q < 2; ++q) {
        ml[4*q] = M[q].x; ml[4*q+1] = M[q].y; ml[4*q+2] = M[q].z; ml[4*q+3] = M[q].w;
    }
#pragma unroll
    for (int l = 0; l < 8; ++l) {
        if (l < LSTART) continue;
        const bool mm = (ml[l] != 0);
        float Tt[5][5];
#pragma unroll
        for (int k = 0; k < 5; ++k)
#pragma unroll
            for (int j = 0; j < 5; ++j) Tt[k][j] = tr[k][j] + xf[5*l + j];
#pragma unroll
        for (int i = 0; i < 5; ++i) {
            float nr[5];
#pragma unroll
            for (int j = 0; j < 5; ++j) {
                float v = A[i][0] + Tt[0][j];
                v = fmaxf(v, A[i][1] + Tt[1][j]);
                v = fmaxf(v, A[i][2] + Tt[2][j]);
                v = fmaxf(v, A[i][3] + Tt[3][j]);
                v = fmaxf(v, A[i][4] + Tt[4][j]);
                nr[j] = v;
            }
#pragma unroll
            for (int j = 0; j < 5; ++j) A[i][j] = mm ? nr[j] : A[i][j];
        }
    }
}

// ---- exact forward over 8 steps, packed backpointer store ----
template<int LSTART>
__device__ __forceinline__ void fwd_block(
    const float4 (&X)[10], const int4 (&M)[2],
    float (&dp)[5], const float (&tr)[5][5],
    uint16_t* __restrict__ dst)
{
    float xf[40];
#pragma unroll
    for (int q = 0; q < 10; ++q) {
        xf[4*q] = X[q].x; xf[4*q+1] = X[q].y; xf[4*q+2] = X[q].z; xf[4*q+3] = X[q].w;
    }
    int ml[8];
#pragma unroll
    for (int q = 0; q < 2; ++q) {
        ml[4*q] = M[q].x; ml[4*q+1] = M[q].y; ml[4*q+2] = M[q].z; ml[4*q+3] = M[q].w;
    }
    uint32_t acc[4];
#pragma unroll
    for (int q = 0; q < 4; ++q) acc[q] = 0;
#pragma unroll
    for (int l = 0; l < 8; ++l) {
        uint32_t pk;
        if (l < LSTART) {
            pk = IDENT;                       // t==0 slot, never applied
        } else {
            const bool mm = (ml[l] != 0);
            float nd[5]; uint32_t pc = 0;
#pragma unroll
            for (int j = 0; j < 5; ++j) {
                float s0 = dp[0] + tr[0][j];
                float s1 = dp[1] + tr[1][j];
                float s2 = dp[2] + tr[2][j];
                float s3 = dp[3] + tr[3][j];
                float s4 = dp[4] + tr[4][j];
                float m = fmaxf(fmaxf(fmaxf(s0, s1), fmaxf(s2, s3)), s4);
                int a = (s0 == m) ? 0 : ((s1 == m) ? 1 : ((s2 == m) ? 2 : ((s3 == m) ? 3 : 4)));
                nd[j] = m + xf[5*l + j];
                pc |= ((uint32_t)a) << (3*j);
            }
#pragma unroll
            for (int j = 0; j < 5; ++j) dp[j] = mm ? nd[j] : dp[j];
            pk = mm ? pc : IDENT;
        }
        acc[l >> 1] |= pk << (16 * (l & 1));
    }
    uint4 st; st.x = acc[0]; st.y = acc[1]; st.z = acc[2]; st.w = acc[3];
    *(uint4*)dst = st;
}

// ================= kernels =================

__global__ __launch_bounds__(256) void k_compose(
    const float* __restrict__ x, const int* __restrict__ mask,
    const float* __restrict__ transform, float* __restrict__ A)
{
    int tid = blockIdx.x * 256 + threadIdx.x;
    int b = tid & (B_ - 1), c = tid >> 11;
    float tr[5][5];
#pragma unroll
    for (int i = 0; i < 5; ++i)
#pragma unroll
        for (int j = 0; j < 5; ++j) tr[i][j] = transform[i*TD + j];

    const float* xb = x + ((size_t)b * T_ + (size_t)c * L_) * 5;
    const int*   mb = mask + (size_t)b * T_ + c * L_;

    float Am[5][5];
#pragma unroll
    for (int i = 0; i < 5; ++i)
#pragma unroll
        for (int j = 0; j < 5; ++j) Am[i][j] = (i == j) ? 0.f : -1e30f;

    float4 XA[10], XB[10]; int4 MA[2], MB[2];
    loadx(xb, mb, 0, XA, MA);
    loadx(xb, mb, 1, XB, MB);
    if (c == 0) compose_block<1>(XA, MA, Am, tr); else compose_block<0>(XA, MA, Am, tr);
    for (int k = 1; k < NB - 1; k += 2) {
        loadx(xb, mb, k + 1, XA, MA);
        compose_block<0>(XB, MB, Am, tr);
        loadx(xb, mb, k + 2, XB, MB);
        compose_block<0>(XA, MA, Am, tr);
    }
    compose_block<0>(XB, MB, Am, tr);

#pragma unroll
    for (int i = 0; i < 5; ++i)
#pragma unroll
        for (int j = 0; j < 5; ++j)
            A[((size_t)c * 25 + i*5 + j) * B_ + b] = Am[i][j];
}

__global__ __launch_bounds__(64) void k_scan(
    const float* __restrict__ x, const float* __restrict__ transform,
    const float* __restrict__ A, float* __restrict__ dps)
{
    int b = blockIdx.x * 64 + threadIdx.x;
    float dp[5];
#pragma unroll
    for (int j = 0; j < 5; ++j) dp[j] = x[(size_t)b * T_ * 5 + j] + transform[5*TD + j];
#pragma unroll
    for (int j = 0; j < 5; ++j) dps[(size_t)j * B_ + b] = dp[j];
#pragma unroll 8
    for (int c = 0; c < NCH - 1; ++c) {
        float a[25];
#pragma unroll
        for (int k = 0; k < 25; ++k) a[k] = A[((size_t)c * 25 + k) * B_ + b];
        float nd[5];
#pragma unroll
        for (int j = 0; j < 5; ++j) {
            float v = dp[0] + a[j];
            v = fmaxf(v, dp[1] + a[5 + j]);
            v = fmaxf(v, dp[2] + a[10 + j]);
            v = fmaxf(v, dp[3] + a[15 + j]);
            v = fmaxf(v, dp[4] + a[20 + j]);
            nd[j] = v;
        }
#pragma unroll
        for (int j = 0; j < 5; ++j) { dp[j] = nd[j]; dps[((size_t)(c+1) * 5 + j) * B_ + b] = dp[j]; }
    }
}

__global__ __launch_bounds__(256) void k_fwd(
    const float* __restrict__ x, const int* __restrict__ mask,
    const float* __restrict__ transform, const float* __restrict__ dps,
    uint16_t* __restrict__ bp, uint16_t* __restrict__ sigma,
    float* __restrict__ out, int* __restrict__ lastc)
{
    int tid = blockIdx.x * 256 + threadIdx.x;
    int b = tid & (B_ - 1), c = tid >> 11;
    float tr[5][5];
#pragma unroll
    for (int i = 0; i < 5; ++i)
#pragma unroll
        for (int j = 0; j < 5; ++j) tr[i][j] = transform[i*TD + j];

    const float* xb  = x + ((size_t)b * T_ + (size_t)c * L_) * 5;
    const int*   mb  = mask + (size_t)b * T_ + c * L_;
    uint16_t*    bpb = bp + (size_t)b * T_ + c * L_;

    float dp[5];
#pragma unroll
    for (int j = 0; j < 5; ++j) dp[j] = dps[((size_t)c * 5 + j) * B_ + b];

    float4 XA[10], XB[10]; int4 MA[2], MB[2];
    loadx(xb, mb, 0, XA, MA);
    loadx(xb, mb, 1, XB, MB);
    if (c == 0) fwd_block<1>(XA, MA, dp, tr, bpb); else fwd_block<0>(XA, MA, dp, tr, bpb);
    for (int k = 1; k < NB - 1; k += 2) {
        loadx(xb, mb, k + 1, XA, MA);
        fwd_block<0>(XB, MB, dp, tr, bpb + (size_t)k * 8);
        loadx(xb, mb, k + 2, XB, MB);
        fwd_block<0>(XA, MA, dp, tr, bpb + (size_t)(k + 1) * 8);
    }
    fwd_block<0>(XB, MB, dp, tr, bpb + (size_t)(NB - 1) * 8);

    if (c == NCH - 1) {
        float best = dp[0] + transform[0*TD + 6];
        int   last = 0;
#pragma unroll
        for (int j = 1; j < 5; ++j) {
            float sc = dp[j] + transform[j*TD + 6];
            if (sc > best) { best = sc; last = j; }
        }
        out[b]   = best;
        lastc[b] = last;
    }

    // sigma_c: compose own chunk's backpointers backward (stores are L2-hot)
    uint32_t ww[L_/2];
    const uint4* wp = (const uint4*)bpb;
#pragma unroll
    for (int q = 0; q < L_/8; ++q) {
        uint4 w = wp[q];
        ww[4*q] = w.x; ww[4*q+1] = w.y; ww[4*q+2] = w.z; ww[4*q+3] = w.w;
    }
    int i0 = 0, i1 = 1, i2 = 2, i3 = 3, i4 = 4;
#pragma unroll
    for (int l = L_ - 1; l >= 0; --l) {
        uint32_t p = (ww[l >> 1] >> (16 * (l & 1))) & 0xFFFFu;
        i0 = (p >> (3*i0)) & 7;
        i1 = (p >> (3*i1)) & 7;
        i2 = (p >> (3*i2)) & 7;
        i3 = (p >> (3*i3)) & 7;
        i4 = (p >> (3*i4)) & 7;
    }
    sigma[(size_t)c * B_ + b] =
        (uint16_t)(i0 | (i1 << 3) | (i2 << 6) | (i3 << 9) | (i4 << 12));
}

__global__ __launch_bounds__(64) void k_back(
    const int* __restrict__ lastc, const uint16_t* __restrict__ sigma,
    uint8_t* __restrict__ endc)
{
    int b = blockIdx.x * 64 + threadIdx.x;
    uint32_t sg[NCH];
#pragma unroll
    for (int c = 0; c < NCH; ++c) sg[c] = sigma[(size_t)c * B_ + b];
    int e = lastc[b];
#pragma unroll
    for (int c = NCH - 1; c >= 1; --c) {
        endc[(size_t)c * B_ + b] = (uint8_t)e;
        e = (sg[c] >> (3*e)) & 7;
    }
    endc[b] = (uint8_t)e;
}

__global__ __launch_bounds__(256) void k_path(
    const uint16_t* __restrict__ bp, const uint8_t* __restrict__ endc,
    float* __restrict__ out)
{
    int tid = blockIdx.x * 256 + threadIdx.x;
    int b = tid & (B_ - 1), c = tid >> 11;
    int idx = endc[(size_t)c * B_ + b];
    const uint4* wp = (const uint4*)(bp + (size_t)b * T_ + c * L_);
    uint32_t ww[L_/2];
#pragma unroll
    for (int q = 0; q < L_/8; ++q) {
        uint4 w = wp[q];
        ww[4*q] = w.x; ww[4*q+1] = w.y; ww[4*q+2] = w.z; ww[4*q+3] = w.w;
    }
    float pv[L_];
#pragma unroll
    for (int l = L_ - 1; l >= 0; --l) {
        pv[l] = (float)idx;
        uint32_t p = (ww[l >> 1] >> (16 * (l & 1))) & 0xFFFFu;
        idx = (p >> (3*idx)) & 7;
    }
    float* path = out + B_ + (size_t)b * T_ + c * L_;
#pragma unroll
    for (int q = 0; q < L_/4; ++q) {
        float4 v; v.x = pv[4*q]; v.y = pv[4*q+1]; v.z = pv[4*q+2]; v.w = pv[4*q+3];
        ((float4*)path)[q] = v;
    }
}

extern "C" void kernel_launch(void* const* d_in, const int* in_sizes, int n_in,
                              void* d_out, int out_size, void* d_ws, size_t ws_size,
                              hipStream_t stream) {
    const float* x         = (const float*)d_in[0];
    const int*   mask      = (const int*)d_in[1];
    const float* transform = (const float*)d_in[2];
    float*       out       = (float*)d_out;

    uint8_t* w = (uint8_t*)d_ws;
    // A: NCH*25*B*4 = 12.5 MiB.  bp (8 MiB) ALIASES A — A is dead after k_scan,
    // and k_fwd (which writes bp) runs after k_scan in-stream. Total ws ~15.4 MiB.
    float*    A     = (float*)   w;                                  // 13107200 B
    uint16_t* bp    = (uint16_t*)w;                                  // aliased, 8 MiB
    float*    dps   = (float*)  (w + 13107200u);                     // 2621440 B
    uint16_t* sig   = (uint16_t*)(w + 13107200u + 2621440u);         // 262144 B
    uint8_t*  endc  = (uint8_t*) (w + 13107200u + 2621440u + 262144u);          // 131072 B
    int*      lastc = (int*)     (w + 13107200u + 2621440u + 262144u + 131072u); // 8192 B

    hipLaunchKernelGGL(k_compose, dim3(B_*NCH/256), dim3(256), 0, stream, x, mask, transform, A);
    hipLaunchKernelGGL(k_scan,    dim3(B_/64),      dim3(64),  0, stream, x, transform, A, dps);
    hipLaunchKernelGGL(k_fwd,     dim3(B_*NCH/256), dim3(256), 0, stream, x, mask, transform, dps,
                       bp, sig, out, lastc);
    hipLaunchKernelGGL(k_back,    dim3(B_/64),      dim3(64),  0, stream, lastc, sig, endc);
    hipLaunchKernelGGL(k_path,    dim3(B_*NCH/256), dim3(256), 0, stream, bp, endc, out);
}

// Round 5
// 88.586 us; speedup vs baseline: 1.5138x; 1.5138x over previous
//
#include <hip/hip_runtime.h>
#include <cstdint>

#define B_    2048
#define T_    2048
#define TD    7            // transform leading dim (C+2)
#define NCH   64           // chunks per row
#define L_    32           // chunk length
#define H_    16           // halo (warm-up) steps
#define IDENT 0x4688u      // 0|1<<3|2<<6|3<<9|4<<12

struct Blk { float4 X[10]; int4 M[2]; };   // 8 steps: 40 floats + 8 mask ints

__device__ __forceinline__ void loadblk(const float* __restrict__ xp,
                                        const int* __restrict__ mp, Blk& bk) {
    const float4* px = (const float4*)xp;
#pragma unroll
    for (int q = 0; q < 10; ++q) bk.X[q] = px[q];
    const int4* pm = (const int4*)mp;
    bk.M[0] = pm[0]; bk.M[1] = pm[1];
}

__device__ __forceinline__ void unpack(const Blk& bk, float (&xf)[40], int (&ml)[8]) {
#pragma unroll
    for (int q = 0; q < 10; ++q) {
        xf[4*q]   = bk.X[q].x; xf[4*q+1] = bk.X[q].y;
        xf[4*q+2] = bk.X[q].z; xf[4*q+3] = bk.X[q].w;
    }
    ml[0]=bk.M[0].x; ml[1]=bk.M[0].y; ml[2]=bk.M[0].z; ml[3]=bk.M[0].w;
    ml[4]=bk.M[1].x; ml[5]=bk.M[1].y; ml[6]=bk.M[1].z; ml[7]=bk.M[1].w;
}

// halo: dp update only (no bp/argmax)
template<int LSTART>
__device__ __forceinline__ void halo8(const Blk& bk, float (&dp)[5],
                                      const float (&tr)[5][5]) {
    float xf[40]; int ml[8];
    unpack(bk, xf, ml);
#pragma unroll
    for (int l = 0; l < 8; ++l) {
        if (l < LSTART) continue;
        const bool mm = (ml[l] != 0);
        float nd[5];
#pragma unroll
        for (int j = 0; j < 5; ++j) {
            float v = dp[0] + tr[0][j];
            v = fmaxf(v, dp[1] + tr[1][j]);
            v = fmaxf(v, dp[2] + tr[2][j]);
            v = fmaxf(v, dp[3] + tr[3][j]);
            v = fmaxf(v, dp[4] + tr[4][j]);
            nd[j] = v + xf[5*l + j];
        }
#pragma unroll
        for (int j = 0; j < 5; ++j) dp[j] = mm ? nd[j] : dp[j];
    }
}

// live: exact fwd, packed bp, rho (root map) update. kill forces step 0 masked
// (used for lane 0 / t==0, whose dp is preset to x[0]+tstart).
__device__ __forceinline__ uint4 live8(const Blk& bk, float (&dp)[5], uint32_t& rho,
                                       const float (&tr)[5][5], bool kill) {
    float xf[40]; int ml[8];
    unpack(bk, xf, ml);
    uint32_t acc[4] = {0u,0u,0u,0u};
#pragma unroll
    for (int l = 0; l < 8; ++l) {
        bool mm = (ml[l] != 0);
        if (l == 0) mm = mm && !kill;
        float nd[5]; int aa[5]; uint32_t pk = 0;
#pragma unroll
        for (int j = 0; j < 5; ++j) {
            float s0 = dp[0] + tr[0][j];
            float s1 = dp[1] + tr[1][j];
            float s2 = dp[2] + tr[2][j];
            float s3 = dp[3] + tr[3][j];
            float s4 = dp[4] + tr[4][j];
            float m = fmaxf(fmaxf(fmaxf(s0, s1), fmaxf(s2, s3)), s4);
            int a = (s0 == m) ? 0 : ((s1 == m) ? 1 : ((s2 == m) ? 2 : ((s3 == m) ? 3 : 4)));
            float v = m + xf[5*l + j];
            a = mm ? a : j;               // masked step: identity bp
            nd[j] = mm ? v : dp[j];
            aa[j] = a;
            pk |= ((uint32_t)a) << (3*j);
        }
        uint32_t nr = 0;
#pragma unroll
        for (int j = 0; j < 5; ++j) nr |= ((rho >> (3*aa[j])) & 7u) << (3*j);
        rho = nr;
#pragma unroll
        for (int j = 0; j < 5; ++j) dp[j] = nd[j];
        acc[l >> 1] |= pk << (16 * (l & 1));
    }
    uint4 r; r.x = acc[0]; r.y = acc[1]; r.z = acc[2]; r.w = acc[3];
    return r;
}

__global__ __launch_bounds__(64, 2) void k_main(
    const float* __restrict__ x, const int* __restrict__ mask,
    const float* __restrict__ tf,
    uint4* __restrict__ bp, uint16_t* __restrict__ sigma,
    float* __restrict__ svec, int* __restrict__ lastc)
{
    const int b = blockIdx.x, c = threadIdx.x;
    float tr[5][5], ts[5], te[5];
#pragma unroll
    for (int i = 0; i < 5; ++i)
#pragma unroll
        for (int j = 0; j < 5; ++j) tr[i][j] = tf[i*TD + j];
#pragma unroll
    for (int j = 0; j < 5; ++j) ts[j] = tf[5*TD + j];
#pragma unroll
    for (int j = 0; j < 5; ++j) te[j] = tf[j*TD + 6];

    const float* row  = x + (size_t)b * (T_*5);
    const int*   mrow = mask + (size_t)b * T_;
    const int hs = (c > 0) ? (c*L_ - H_) : 0;   // halo start step
    const int ls = c * L_;                      // live start step

    Blk P, Q, R, S;
    loadblk(row + hs*5,      mrow + hs,     P);
    loadblk(row + hs*5 + 40, mrow + hs + 8, Q);

    float dp[5];
    dp[0]=P.X[0].x; dp[1]=P.X[0].y; dp[2]=P.X[0].z; dp[3]=P.X[0].w; dp[4]=P.X[1].x;
    halo8<1>(P, dp, tr);
    loadblk(row + ls*5,      mrow + ls,     R);
    halo8<0>(Q, dp, tr);
    loadblk(row + ls*5 + 40, mrow + ls + 8, S);

    float dpE[5];
#pragma unroll
    for (int j = 0; j < 5; ++j) dpE[j] = (c == 0) ? 0.0f : dp[j];
    if (c == 0) {   // exact t==0 init; step 0 is then force-masked in live8
        dp[0]=R.X[0].x+ts[0]; dp[1]=R.X[0].y+ts[1]; dp[2]=R.X[0].z+ts[2];
        dp[3]=R.X[0].w+ts[3]; dp[4]=R.X[1].x+ts[4];
    }
    uint32_t rho = IDENT;
    uint4* bpb = bp + (size_t)b*256 + c;        // [b][jblk][c] interleaved

    uint4 o0 = live8(R, dp, rho, tr, c == 0);
    loadblk(row + ls*5 +  80, mrow + ls + 16, P);
    bpb[0] = o0;
    uint4 o1 = live8(S, dp, rho, tr, false);
    loadblk(row + ls*5 + 120, mrow + ls + 24, Q);
    bpb[64] = o1;
    uint4 o2 = live8(P, dp, rho, tr, false);
    bpb[128] = o2;
    uint4 o3 = live8(Q, dp, rho, tr, false);
    bpb[192] = o3;

    sigma[(size_t)c * B_ + b] = (uint16_t)rho;
#pragma unroll
    for (int j = 0; j < 5; ++j) {
        int r = (rho >> (3*j)) & 7;
        float e = dpE[0];
        e = (r == 1) ? dpE[1] : e;
        e = (r == 2) ? dpE[2] : e;
        e = (r == 3) ? dpE[3] : e;
        e = (r == 4) ? dpE[4] : e;
        svec[((size_t)c*5 + j) * B_ + b] = dp[j] - e;   // exact segment score
    }
    if (c == NCH - 1) {
        float best = dp[0] + te[0]; int last = 0;
#pragma unroll
        for (int j = 1; j < 5; ++j) {
            float sc = dp[j] + te[j];
            if (sc > best) { best = sc; last = j; }
        }
        lastc[b] = last;
    }
}

__global__ __launch_bounds__(64) void k_back(
    const uint16_t* __restrict__ sigma, const float* __restrict__ svec,
    const int* __restrict__ lastc, const float* __restrict__ tf,
    uint8_t* __restrict__ endc, float* __restrict__ out)
{
    int b = blockIdx.x*64 + threadIdx.x;
    uint32_t sg[NCH];
#pragma unroll
    for (int c = 0; c < NCH; ++c) sg[c] = sigma[(size_t)c*B_ + b];
    int ec[NCH];
    int e = lastc[b];
#pragma unroll
    for (int c = NCH-1; c >= 0; --c) {
        ec[c] = e;
        e = (sg[c] >> (3*e)) & 7;
    }
    uint8_t* eb = endc + (size_t)b*NCH;
#pragma unroll
    for (int c = 0; c < NCH; ++c) eb[c] = (uint8_t)ec[c];
    float sum = 0.f;
#pragma unroll
    for (int c = 0; c < NCH; ++c) sum += svec[((size_t)c*5 + ec[c]) * B_ + b];
    out[b] = sum + tf[ec[NCH-1]*TD + 6];
}

__global__ __launch_bounds__(256) void k_path(
    const uint4* __restrict__ bp, const uint8_t* __restrict__ endc,
    float* __restrict__ out)
{
    int tid = blockIdx.x*256 + threadIdx.x;
    int b = tid >> 6, c = tid & 63;
    int idx = endc[(size_t)b*NCH + c];
    uint32_t pk[32];
#pragma unroll
    for (int j = 0; j < 4; ++j) {
        uint4 w = bp[((size_t)b*4 + j)*64 + c];
        pk[8*j+0] = w.x & 0xffffu; pk[8*j+1] = w.x >> 16;
        pk[8*j+2] = w.y & 0xffffu; pk[8*j+3] = w.y >> 16;
        pk[8*j+4] = w.z & 0xffffu; pk[8*j+5] = w.z >> 16;
        pk[8*j+6] = w.w & 0xffffu; pk[8*j+7] = w.w >> 16;
    }
    float pv[32];
#pragma unroll
    for (int l = 31; l >= 0; --l) {
        pv[l] = (float)idx;
        idx = (pk[l] >> (3*idx)) & 7;
    }
    float* path = out + B_ + (size_t)b*T_ + c*L_;
#pragma unroll
    for (int q = 0; q < 8; ++q) {
        float4 v; v.x = pv[4*q]; v.y = pv[4*q+1]; v.z = pv[4*q+2]; v.w = pv[4*q+3];
        ((float4*)path)[q] = v;
    }
}

extern "C" void kernel_launch(void* const* d_in, const int* in_sizes, int n_in,
                              void* d_out, int out_size, void* d_ws, size_t ws_size,
                              hipStream_t stream) {
    const float* x         = (const float*)d_in[0];
    const int*   mask      = (const int*)d_in[1];
    const float* transform = (const float*)d_in[2];
    float*       out       = (float*)d_out;

    uint8_t* w = (uint8_t*)d_ws;
    uint4*    bp    = (uint4*)    w;                        // 8 MiB
    uint16_t* sigma = (uint16_t*)(w + 8388608u);            // 256 KiB
    float*    svec  = (float*)   (w + 8650752u);            // 2.5 MiB
    uint8_t*  endc  =            (w + 11272192u);           // 128 KiB
    int*      lastc = (int*)     (w + 11403264u);           // 8 KiB

    hipLaunchKernelGGL(k_main, dim3(B_),        dim3(64),  0, stream,
                       x, mask, transform, bp, sigma, svec, lastc);
    hipLaunchKernelGGL(k_back, dim3(B_/64),     dim3(64),  0, stream,
                       sigma, svec, lastc, transform, endc, out);
    hipLaunchKernelGGL(k_path, dim3(B_*64/256), dim3(256), 0, stream,
                       bp, endc, out);
}

// Round 6
// 45.254 us; speedup vs baseline: 2.9634x; 1.9575x over previous
//
#include <hip/hip_runtime.h>
#include <cstdint>

#define B_    2048
#define T_    2048
#define TD    7                 // transform leading dim (C+2)
#define NCHK  256               // chunks per row (= threads per block)
#define L_    8                 // steps per chunk
#define IDENT 0x4688u           // 0|1<<3|2<<6|3<<9|4<<12

// skewed LDS layout for x: dword addr = 5t + (t>>3) + j
// lane stride per chunk = 41 dwords == 9 (mod 32), coprime -> 2 lanes/bank, free
__device__ __forceinline__ int xaddr(int t) { return 5 * t + (t >> 3); }

// compose packed maps: r[j] = f[g[j]]
__device__ __forceinline__ uint32_t mcompose(uint32_t f, uint32_t g) {
    uint32_t r = 0;
#pragma unroll
    for (int j = 0; j < 5; ++j) {
        uint32_t gj = (g >> (3 * j)) & 7u;
        r |= ((f >> (3 * gj)) & 7u) << (3 * j);
    }
    return r;
}

__global__ __launch_bounds__(256) void k_all(
    const float* __restrict__ x, const int* __restrict__ mask,
    const float* __restrict__ tf, float* __restrict__ out)
{
    __shared__ float   xs[10500];     // 41 KiB (skewed row)
    __shared__ uint8_t ms[2048];      // mask bytes
    __shared__ uint32_t Ml[NCHK];     // scan maps
    __shared__ float   part[4];
    __shared__ int     lastS;

    const int b = blockIdx.x, c = threadIdx.x;

    // ---- stage x (coalesced 16B/lane) into skewed LDS ----
    const float4* gx = (const float4*)(x + (size_t)b * (T_ * 5));
#pragma unroll
    for (int q = 0; q < 10; ++q) {
        int fi = c + 256 * q;            // float4 index in row
        float4 v = gx[fi];
        int g = 4 * fi;                  // dword offset in row
        int base = g + fi / 10;          // +1 skew per 40-dword chunk
        xs[base + 0] = v.x; xs[base + 1] = v.y;
        xs[base + 2] = v.z; xs[base + 3] = v.w;
    }
    // ---- stage mask as bytes (coalesced 32B/lane) ----
    {
        const int4* gm = ((const int4*)(mask + (size_t)b * T_)) + 2 * c;
        int4 a = gm[0], d = gm[1];
        uint32_t w0 = (a.x ? 1u : 0u) | ((a.y ? 1u : 0u) << 8) |
                      ((a.z ? 1u : 0u) << 16) | ((a.w ? 1u : 0u) << 24);
        uint32_t w1 = (d.x ? 1u : 0u) | ((d.y ? 1u : 0u) << 8) |
                      ((d.z ? 1u : 0u) << 16) | ((d.w ? 1u : 0u) << 24);
        ((uint32_t*)ms)[2 * c]     = w0;
        ((uint32_t*)ms)[2 * c + 1] = w1;
    }

    float tr[5][5], ts[5], te[5];
#pragma unroll
    for (int i = 0; i < 5; ++i)
#pragma unroll
        for (int j = 0; j < 5; ++j) tr[i][j] = tf[i * TD + j];
#pragma unroll
    for (int j = 0; j < 5; ++j) ts[j] = tf[5 * TD + j];
#pragma unroll
    for (int j = 0; j < 5; ++j) te[j] = tf[j * TD + 6];

    __syncthreads();

    // ---- halo warm-up (15 predicated steps; lanes c<=2 are exact) ----
    int s0 = 8 * c - 16; if (s0 < 0) s0 = 0;
    float dp[5];
    {
        int a0 = xaddr(s0);
#pragma unroll
        for (int j = 0; j < 5; ++j) dp[j] = xs[a0 + j];
        if (s0 == 0) {
#pragma unroll
            for (int j = 0; j < 5; ++j) dp[j] += ts[j];
        }
    }
#pragma unroll 5
    for (int h = 1; h <= 15; ++h) {
        int t = s0 + h;
        bool mm = (t < 8 * c) && (ms[t] != 0);
        int at = xaddr(t);
        float nd[5];
#pragma unroll
        for (int j = 0; j < 5; ++j) {
            float v = dp[0] + tr[0][j];
            v = fmaxf(v, dp[1] + tr[1][j]);
            v = fmaxf(v, dp[2] + tr[2][j]);
            v = fmaxf(v, dp[3] + tr[3][j]);
            v = fmaxf(v, dp[4] + tr[4][j]);
            nd[j] = v + xs[at + j];
        }
#pragma unroll
        for (int j = 0; j < 5; ++j) dp[j] = mm ? nd[j] : dp[j];
    }

    float dpE[5];
#pragma unroll
    for (int j = 0; j < 5; ++j) dpE[j] = (c == 0) ? 0.0f : dp[j];

    // ---- live: exact forward over 8 steps, bp kept in registers ----
    uint32_t acc[4] = {0u, 0u, 0u, 0u};
    uint32_t rho = IDENT;
#pragma unroll
    for (int l = 0; l < L_; ++l) {
        int t = 8 * c + l;
        bool mm = (ms[t] != 0) && !(c == 0 && l == 0);
        int at = xaddr(t);
        float nd[5]; int aa[5]; uint32_t pk = 0;
#pragma unroll
        for (int j = 0; j < 5; ++j) {
            float sA = dp[0] + tr[0][j];
            float sB = dp[1] + tr[1][j];
            float sC = dp[2] + tr[2][j];
            float sD = dp[3] + tr[3][j];
            float sE = dp[4] + tr[4][j];
            float m = fmaxf(fmaxf(fmaxf(sA, sB), fmaxf(sC, sD)), sE);
            int a = (sA == m) ? 0 : ((sB == m) ? 1 : ((sC == m) ? 2 : ((sD == m) ? 3 : 4)));
            float v = m + xs[at + j];
            a = mm ? a : j;
            nd[j] = mm ? v : dp[j];
            aa[j] = a;
            pk |= ((uint32_t)a) << (3 * j);
        }
        uint32_t nr = 0;
#pragma unroll
        for (int j = 0; j < 5; ++j) nr |= ((rho >> (3 * aa[j])) & 7u) << (3 * j);
        rho = nr;
#pragma unroll
        for (int j = 0; j < 5; ++j) dp[j] = nd[j];
        acc[l >> 1] |= pk << (16 * (l & 1));
    }

    // exact per-chunk segment score (within-lane offset cancels)
    float svec[5];
#pragma unroll
    for (int j = 0; j < 5; ++j) {
        int r = (rho >> (3 * j)) & 7;
        float e = dpE[0];
        e = (r == 1) ? dpE[1] : e;
        e = (r == 2) ? dpE[2] : e;
        e = (r == 3) ? dpE[3] : e;
        e = (r == 4) ? dpE[4] : e;
        svec[j] = dp[j] - e;
    }

    __syncthreads();            // mask reads done; reuse small LDS
    Ml[c] = rho;                // publish sigma_c
    if (c == NCHK - 1) {
        float best = dp[0] + te[0]; int last = 0;
#pragma unroll
        for (int j = 1; j < 5; ++j) {
            float sc = dp[j] + te[j];
            if (sc > best) { best = sc; last = j; }
        }
        lastS = last;
    }
    __syncthreads();

    const int last = lastS;
    // suffix scan: M[c] = sigma_{c+1} o ... o sigma_{255}
    uint32_t Mreg = (c < NCHK - 1) ? Ml[c + 1] : IDENT;
#pragma unroll
    for (int d = 1; d < NCHK; d <<= 1) {
        __syncthreads();
        Ml[c] = Mreg;
        __syncthreads();
        uint32_t other = (c + d < NCHK) ? Ml[c + d] : IDENT;
        Mreg = mcompose(Mreg, other);
    }
    const int ec = (Mreg >> (3 * last)) & 7;   // class at end of chunk c

    // ---- exact telescoped score: block reduction ----
    {
        float v0 = svec[0];
        v0 = (ec == 1) ? svec[1] : v0;
        v0 = (ec == 2) ? svec[2] : v0;
        v0 = (ec == 3) ? svec[3] : v0;
        v0 = (ec == 4) ? svec[4] : v0;
        if (c == NCHK - 1) v0 += te[last];
#pragma unroll
        for (int off = 1; off < 64; off <<= 1) v0 += __shfl_xor(v0, off);
        if ((c & 63) == 0) part[c >> 6] = v0;
        __syncthreads();
        if (c == 0) out[b] = (part[0] + part[1]) + (part[2] + part[3]);
    }

    // ---- path decode from register bp ----
    float pv[L_];
    int e = ec;
#pragma unroll
    for (int l = L_ - 1; l >= 0; --l) {
        pv[l] = (float)e;
        uint32_t p = (acc[l >> 1] >> (16 * (l & 1))) & 0xFFFFu;
        e = (p >> (3 * e)) & 7;
    }
    float* path = out + B_ + (size_t)b * T_ + c * L_;
    float4 v0; v0.x = pv[0]; v0.y = pv[1]; v0.z = pv[2]; v0.w = pv[3];
    float4 v1; v1.x = pv[4]; v1.y = pv[5]; v1.z = pv[6]; v1.w = pv[7];
    ((float4*)path)[0] = v0;
    ((float4*)path)[1] = v1;
}

extern "C" void kernel_launch(void* const* d_in, const int* in_sizes, int n_in,
                              void* d_out, int out_size, void* d_ws, size_t ws_size,
                              hipStream_t stream) {
    const float* x         = (const float*)d_in[0];
    const int*   mask      = (const int*)d_in[1];
    const float* transform = (const float*)d_in[2];
    float*       out       = (float*)d_out;

    hipLaunchKernelGGL(k_all, dim3(B_), dim3(256), 0, stream,
                       x, mask, transform, out);
}

// Round 7
// 40.124 us; speedup vs baseline: 3.3423x; 1.1279x over previous
//
#include <hip/hip_runtime.h>
#include <cstdint>

#define B_    2048
#define T_    2048
#define TD    7
#define IDENT 0x4688u    // identity map: 0|1<<3|2<<6|3<<9|4<<12

// compose packed 5-slot maps: r[j] = f[g[j]]
__device__ __forceinline__ uint32_t mcompose(uint32_t f, uint32_t g) {
    uint32_t r = 0;
#pragma unroll
    for (int j = 0; j < 5; ++j) {
        uint32_t gj = (g >> (3 * j)) & 7u;
        r |= ((f >> (3 * gj)) & 7u) << (3 * j);
    }
    return r;
}

// f32 -> bf16 round-to-nearest-even
__device__ __forceinline__ uint32_t f2bf(float f) {
    uint32_t u = __float_as_uint(f);
    return (u + 0x7FFFu + ((u >> 16) & 1u)) >> 16;
}

__device__ __forceinline__ float bfld(const uint16_t* __restrict__ xs, int h) {
    return __uint_as_float(((uint32_t)xs[h]) << 16);
}

// halo warm-up (15 steps) + exact live forward (8 steps), bp in registers.
// skewed layout h(t,j) = 5t + 2*(t>>3) + j -> lane stride 21 dwords (bank-free)
template<bool AM>
__device__ __forceinline__ void fwd_chunk(
    const uint16_t* __restrict__ xs, const uint8_t* __restrict__ ms, int c,
    const float (&tr)[5][5], const float (&ts)[5],
    float (&dp)[5], float (&dpE)[5], uint32_t (&acc)[4], uint32_t& rho)
{
    int s0 = 8 * c - 16; if (s0 < 0) s0 = 0;
    int a0 = 5 * s0 + 2 * (s0 >> 3);
#pragma unroll
    for (int j = 0; j < 5; ++j) dp[j] = bfld(xs, a0 + j);
    if (s0 == 0) {
#pragma unroll
        for (int j = 0; j < 5; ++j) dp[j] += ts[j];   // lanes 0..2 exact start
    }
#pragma unroll
    for (int h = 1; h <= 15; ++h) {
        int t = s0 + h;
        bool mm = t < 8 * c;
        if (!AM) mm = mm && (((ms[t >> 3] >> (t & 7)) & 1) != 0);
        int at = 5 * t + 2 * (t >> 3);
        float nd[5];
#pragma unroll
        for (int j = 0; j < 5; ++j) {
            float v = fmaxf(fmaxf(fmaxf(fmaxf(dp[0] + tr[0][j], dp[1] + tr[1][j]),
                                        dp[2] + tr[2][j]), dp[3] + tr[3][j]),
                            dp[4] + tr[4][j]);
            nd[j] = v + bfld(xs, at + j);
        }
#pragma unroll
        for (int j = 0; j < 5; ++j) dp[j] = mm ? nd[j] : dp[j];
    }
#pragma unroll
    for (int j = 0; j < 5; ++j) dpE[j] = (c == 0) ? 0.0f : dp[j];

    rho = IDENT;
    acc[0] = acc[1] = acc[2] = acc[3] = 0u;
    const uint32_t mb = AM ? 0xFFu : (uint32_t)ms[c];
#pragma unroll
    for (int l = 0; l < 8; ++l) {
        bool mm = ((mb >> l) & 1u) != 0;
        if (c == 0 && l == 0) mm = false;          // t==0: dp preset, identity bp
        int at = 42 * c + 5 * l;                   // = 5t + 2*(t>>3) for live t
        float nd[5]; int aa[5]; uint32_t pk = 0;
#pragma unroll
        for (int j = 0; j < 5; ++j) {
            float sA = dp[0] + tr[0][j];
            float sB = dp[1] + tr[1][j];
            float sC = dp[2] + tr[2][j];
            float sD = dp[3] + tr[3][j];
            float sE = dp[4] + tr[4][j];
            float m = fmaxf(fmaxf(fmaxf(fmaxf(sA, sB), sC), sD), sE);
            int a = (sA == m) ? 0 : ((sB == m) ? 1 : ((sC == m) ? 2 : ((sD == m) ? 3 : 4)));
            float v = m + bfld(xs, at + j);
            a = mm ? a : j;
            nd[j] = mm ? v : dp[j];
            aa[j] = a;
            pk |= ((uint32_t)a) << (3 * j);
        }
        uint32_t nr = 0;
#pragma unroll
        for (int j = 0; j < 5; ++j) nr |= ((rho >> (3 * aa[j])) & 7u) << (3 * j);
        rho = nr;
#pragma unroll
        for (int j = 0; j < 5; ++j) dp[j] = nd[j];
        acc[l >> 1] |= pk << (16 * (l & 1));
    }
}

__global__ __launch_bounds__(256) void k_all(
    const float* __restrict__ x, const int* __restrict__ mask,
    const float* __restrict__ tf, float* __restrict__ out)
{
    __shared__ uint16_t xs[10752];   // bf16 skewed row, 21 KiB
    __shared__ uint8_t  ms[256];     // mask bits (1 byte = 8 steps)
    __shared__ uint32_t tot[4];
    __shared__ float    part[4];
    __shared__ int      lastS;

    const int b = blockIdx.x, c = threadIdx.x;
    const int lane = c & 63, w = c >> 6;

    // ---- stage x coalesced, convert to bf16, skewed pair-writes ----
    const float4* gx = (const float4*)(x + (size_t)b * (T_ * 5));
#pragma unroll
    for (int q = 0; q < 10; ++q) {
        int fi = c + 256 * q;
        float4 v = gx[fi];
        int e0 = 4 * fi;
        int k  = (e0 * 52429) >> 21;            // e0/40 (= t>>3), exact for e0<64k
        int h0 = e0 + 2 * k;                    // even -> 4B aligned pair writes
        *(uint32_t*)(xs + h0)     = f2bf(v.x) | (f2bf(v.y) << 16);
        *(uint32_t*)(xs + h0 + 2) = f2bf(v.z) | (f2bf(v.w) << 16);
    }
    // ---- stage mask as bits; detect all-ones row ----
    uint32_t mbits;
    {
        const int4* gm = ((const int4*)(mask + (size_t)b * T_)) + 2 * c;
        int4 a = gm[0], d = gm[1];
        mbits = (a.x ? 1u : 0u) | (a.y ? 2u : 0u) | (a.z ? 4u : 0u) | (a.w ? 8u : 0u)
              | (d.x ? 16u : 0u) | (d.y ? 32u : 0u) | (d.z ? 64u : 0u) | (d.w ? 128u : 0u);
        ms[c] = (uint8_t)mbits;
    }

    float tr[5][5], ts[5], te[5];
#pragma unroll
    for (int i = 0; i < 5; ++i)
#pragma unroll
        for (int j = 0; j < 5; ++j) tr[i][j] = tf[i * TD + j];
#pragma unroll
    for (int j = 0; j < 5; ++j) ts[j] = tf[5 * TD + j];
#pragma unroll
    for (int j = 0; j < 5; ++j) te[j] = tf[j * TD + 6];

    const int allones = __syncthreads_and(mbits == 0xFFu);   // barrier + vote

    float dp[5], dpE[5]; uint32_t acc[4], rho;
    if (allones) fwd_chunk<true >(xs, ms, c, tr, ts, dp, dpE, acc, rho);
    else         fwd_chunk<false>(xs, ms, c, tr, ts, dp, dpE, acc, rho);

    // exact per-chunk segment score (within-lane telescoping)
    float svec[5];
#pragma unroll
    for (int j = 0; j < 5; ++j) {
        int r = (rho >> (3 * j)) & 7;
        float e = dpE[0];
        e = (r == 1) ? dpE[1] : e;
        e = (r == 2) ? dpE[2] : e;
        e = (r == 3) ? dpE[3] : e;
        e = (r == 4) ? dpE[4] : e;
        svec[j] = dp[j] - e;
    }

    // ---- intra-wave inclusive suffix composition via shfl (no barriers) ----
    uint32_t I = rho;
#pragma unroll
    for (int d = 1; d < 64; d <<= 1) {
        uint32_t oth = __shfl_down(I, d);
        uint32_t cm  = mcompose(I, oth);
        I = (lane + d < 64) ? cm : I;
    }
    if (lane == 0) tot[w] = I;        // wave total = sigma_first o ... o sigma_last
    if (c == 255) {
        float best = dp[0] + te[0]; int last = 0;
#pragma unroll
        for (int j = 1; j < 5; ++j) {
            float s = dp[j] + te[j];
            if (s > best) { best = s; last = j; }
        }
        lastS = last;
    }
    __syncthreads();

    uint32_t Tw = IDENT;              // composition of later waves' totals
    if (w < 3) Tw = tot[w + 1];
    if (w < 2) Tw = mcompose(Tw, tot[w + 2]);
    if (w < 1) Tw = mcompose(Tw, tot[w + 3]);
    uint32_t Ex = __shfl_down(I, 1);  // exclusive within wave
    uint32_t M  = (lane < 63) ? mcompose(Ex, Tw) : Tw;
    const int last = lastS;
    const int ec = (M >> (3 * last)) & 7;   // class at end of chunk c

    // ---- exact telescoped score: wave reduce + 4 partials ----
    {
        float v = svec[0];
        v = (ec == 1) ? svec[1] : v;
        v = (ec == 2) ? svec[2] : v;
        v = (ec == 3) ? svec[3] : v;
        v = (ec == 4) ? svec[4] : v;
        if (c == 255) v += te[last];
#pragma unroll
        for (int off = 1; off < 64; off <<= 1) v += __shfl_xor(v, off);
        if (lane == 0) part[w] = v;
    }
    __syncthreads();
    if (c == 0) out[b] = (part[0] + part[1]) + (part[2] + part[3]);

    // ---- path decode from register bp ----
    float pv[8];
    int e = ec;
#pragma unroll
    for (int l = 7; l >= 0; --l) {
        pv[l] = (float)e;
        uint32_t p = (acc[l >> 1] >> (16 * (l & 1))) & 0xFFFFu;
        e = (p >> (3 * e)) & 7;
    }
    float* path = out + B_ + (size_t)b * T_ + c * 8;
    float4 v0; v0.x = pv[0]; v0.y = pv[1]; v0.z = pv[2]; v0.w = pv[3];
    float4 v1; v1.x = pv[4]; v1.y = pv[5]; v1.z = pv[6]; v1.w = pv[7];
    ((float4*)path)[0] = v0;
    ((float4*)path)[1] = v1;
}

extern "C" void kernel_launch(void* const* d_in, const int* in_sizes, int n_in,
                              void* d_out, int out_size, void* d_ws, size_t ws_size,
                              hipStream_t stream) {
    const float* x         = (const float*)d_in[0];
    const int*   mask      = (const int*)d_in[1];
    const float* transform = (const float*)d_in[2];
    float*       out       = (float*)d_out;

    hipLaunchKernelGGL(k_all, dim3(B_), dim3(256), 0, stream,
                       x, mask, transform, out);
}